// Round 1
// baseline (99.229 us; speedup 1.0000x reference)
//
#include <hip/hip_runtime.h>

#define TPB 256
#define NOBS_MAX 29696   // >= 29492 observed values, padded

__device__ __forceinline__ unsigned long long umin64(unsigned long long a, unsigned long long b) { return a < b ? a : b; }
__device__ __forceinline__ unsigned long long umax64(unsigned long long a, unsigned long long b) { return a > b ? a : b; }

// Kernel A: copy X -> out (vectorized float4, with scalar tail guard)
__global__ void knn_copy_kernel(const float* __restrict__ src, float* __restrict__ dst, int n, int n4) {
    int i = blockIdx.x * blockDim.x + threadIdx.x;
    if (i < n4) {
        reinterpret_cast<float4*>(dst)[i] = reinterpret_cast<const float4*>(src)[i];
    }
    if (i == 0) {
        for (int t = n4 * 4; t < n; ++t) dst[t] = src[t];
    }
}

// Kernel B: compute the (single) imputed scalar v via 3 fixed-point iterations,
// then scatter it to all missing positions.
__global__ void __launch_bounds__(TPB) knn_impute_kernel(const float* __restrict__ X,
                                                         const int* __restrict__ miss_idx,
                                                         const int* __restrict__ obs_idx,
                                                         float* __restrict__ out,
                                                         int n_obs, int n_miss) {
    __shared__ float obs_s[NOBS_MAX];             // ~116 KiB
    __shared__ unsigned long long sk[TPB * 5];    // 10 KiB merge scratch
    __shared__ float v_sh;
    const int tid = threadIdx.x;

    // Stage observed values into LDS (obs_idx is sorted -> near-coalesced gather).
    for (int j = tid; j < n_obs; j += TPB) obs_s[j] = X[obs_idx[j]];
    __syncthreads();

    float v = 0.0f;  // reference initializes missing values to 0
    for (int it = 0; it < 3; ++it) {
        // Per-thread top-5 smallest keys, key = (f32 bits of dist << 32) | index.
        // dist >= 0 so bit pattern is order-preserving; low index wins ties,
        // exactly matching jax.lax.top_k(-d, 5) semantics.
        unsigned long long k0 = ~0ull, k1 = ~0ull, k2 = ~0ull, k3 = ~0ull, k4 = ~0ull;
        for (int j = tid; j < n_obs; j += TPB) {
            float diff = v - obs_s[j];
            float d = diff * diff;
            unsigned long long key =
                ((unsigned long long)__float_as_uint(d) << 32) | (unsigned int)j;
            if (key < k4) {   // most candidates fail here: 1 compare
                k4 = key;
                unsigned long long t;
                if (k4 < k3) { t = k3; k3 = k4; k4 = t; }
                if (k3 < k2) { t = k2; k2 = k3; k3 = t; }
                if (k2 < k1) { t = k1; k1 = k2; k2 = t; }
                if (k1 < k0) { t = k0; k0 = k1; k1 = t; }
            }
        }
        sk[tid * 5 + 0] = k0; sk[tid * 5 + 1] = k1; sk[tid * 5 + 2] = k2;
        sk[tid * 5 + 3] = k3; sk[tid * 5 + 4] = k4;
        __syncthreads();

        // Tree-merge 256 sorted 5-lists. Branchless order-statistic merge:
        // merged[k] = min over i+j=k-1 (i,j >= -1) of max(a_i, b_j).
        // Readers [off,2off) and writers [0,off) are disjoint -> 1 barrier/round.
        for (int off = TPB / 2; off >= 1; off >>= 1) {
            if (tid < off) {
                const int pa = tid * 5, pb = (tid + off) * 5;
                unsigned long long a0 = sk[pa + 0], a1 = sk[pa + 1], a2 = sk[pa + 2],
                                   a3 = sk[pa + 3], a4 = sk[pa + 4];
                unsigned long long b0 = sk[pb + 0], b1 = sk[pb + 1], b2 = sk[pb + 2],
                                   b3 = sk[pb + 3], b4 = sk[pb + 4];
                unsigned long long m0 = umin64(a0, b0);
                unsigned long long m1 = umin64(umin64(a1, b1), umax64(a0, b0));
                unsigned long long m2 = umin64(umin64(a2, b2),
                                        umin64(umax64(a0, b1), umax64(a1, b0)));
                unsigned long long m3 = umin64(umin64(a3, b3),
                                        umin64(umin64(umax64(a0, b2), umax64(a1, b1)),
                                               umax64(a2, b0)));
                unsigned long long m4 = umin64(umin64(a4, b4),
                                        umin64(umin64(umax64(a0, b3), umax64(a1, b2)),
                                               umin64(umax64(a2, b1), umax64(a3, b0))));
                sk[pa + 0] = m0; sk[pa + 1] = m1; sk[pa + 2] = m2;
                sk[pa + 3] = m3; sk[pa + 4] = m4;
            }
            __syncthreads();
        }

        if (tid == 0) {
            // Sum in ascending-distance order (matches reference's gather order).
            float s = obs_s[(unsigned int)(sk[0] & 0xFFFFFFFFull)];
            s += obs_s[(unsigned int)(sk[1] & 0xFFFFFFFFull)];
            s += obs_s[(unsigned int)(sk[2] & 0xFFFFFFFFull)];
            s += obs_s[(unsigned int)(sk[3] & 0xFFFFFFFFull)];
            s += obs_s[(unsigned int)(sk[4] & 0xFFFFFFFFull)];
            v_sh = s / 5.0f;
        }
        __syncthreads();
        v = v_sh;
        __syncthreads();
    }

    // Scatter the single imputed value to all missing positions.
    for (int j = tid; j < n_miss; j += TPB) out[miss_idx[j]] = v;
}

extern "C" void kernel_launch(void* const* d_in, const int* in_sizes, int n_in,
                              void* d_out, int out_size, void* d_ws, size_t ws_size,
                              hipStream_t stream) {
    const float* X        = (const float*)d_in[0];
    const int*   miss_idx = (const int*)d_in[1];
    const int*   obs_idx  = (const int*)d_in[2];
    float*       out      = (float*)d_out;

    const int n_miss = in_sizes[1];
    const int n_obs  = in_sizes[2];
    const int n      = out_size;
    const int n4     = n / 4;

    knn_copy_kernel<<<(n4 + TPB - 1) / TPB, TPB, 0, stream>>>(X, out, n, n4);
    knn_impute_kernel<<<1, TPB, 0, stream>>>(X, miss_idx, obs_idx, out, n_obs, n_miss);
}

// Round 2
// 46.694 us; speedup vs baseline: 2.1251x; 2.1251x over previous
//
#include <hip/hip_runtime.h>

#define TPB 1024
#define NPT 29            // ceil(29492 / 1024); NPT*TPB = 29696 >= n_obs
#define NOBS_MAX 29696
#define NWAVE (TPB / 64)

typedef unsigned long long ull;

__device__ __forceinline__ ull umin64(ull a, ull b) { return a < b ? a : b; }
__device__ __forceinline__ ull umax64(ull a, ull b) { return a > b ? a : b; }

// Branchless order-statistic merge of two sorted 5-lists (ascending):
// merged[k] = min over i+j=k-1 of max(a_i, b_j). Keys are unique
// ((dist_bits<<32)|index), so ties are impossible and ordering is total.
__device__ __forceinline__ void merge5(ull& a0, ull& a1, ull& a2, ull& a3, ull& a4,
                                       ull b0, ull b1, ull b2, ull b3, ull b4) {
    ull m0 = umin64(a0, b0);
    ull m1 = umin64(umin64(a1, b1), umax64(a0, b0));
    ull m2 = umin64(umin64(a2, b2), umin64(umax64(a0, b1), umax64(a1, b0)));
    ull m3 = umin64(umin64(a3, b3),
                    umin64(umin64(umax64(a0, b2), umax64(a1, b1)), umax64(a2, b0)));
    ull m4 = umin64(umin64(a4, b4),
                    umin64(umin64(umax64(a0, b3), umax64(a1, b2)),
                           umin64(umax64(a2, b1), umax64(a3, b0))));
    a0 = m0; a1 = m1; a2 = m2; a3 = m3; a4 = m4;
}

__device__ __forceinline__ void insert5(ull key, ull& k0, ull& k1, ull& k2, ull& k3, ull& k4) {
    if (key < k4) {
        k4 = key;
        ull t;
        if (k4 < k3) { t = k3; k3 = k4; k4 = t; }
        if (k3 < k2) { t = k2; k2 = k3; k3 = t; }
        if (k2 < k1) { t = k1; k1 = k2; k2 = t; }
        if (k1 < k0) { t = k0; k0 = k1; k1 = t; }
    }
}

__global__ void __launch_bounds__(TPB) knn_fused_kernel(const float* __restrict__ X,
                                                        const int* __restrict__ miss_idx,
                                                        const int* __restrict__ obs_idx,
                                                        float* __restrict__ out,
                                                        int n, int n_obs, int n_miss) {
    __shared__ float obs_s[NOBS_MAX];       // value lookup for the final mean
    __shared__ ull   sk[NWAVE * 5];         // per-wave top-5 keys
    __shared__ float v_sh;

    const int tid  = threadIdx.x;
    const int wid  = tid >> 6;
    const int lane = tid & 63;

    // ---- Phase 0: copy X -> out (float4), overlaps with gather latency ----
    const int n4 = n >> 2;
    for (int i = tid; i < n4; i += TPB)
        reinterpret_cast<float4*>(out)[i] = reinterpret_cast<const float4*>(X)[i];
    for (int t = n4 * 4 + tid; t < n; t += TPB) out[t] = X[t];

    // ---- Phase 1: gather observed values into registers (2 independent
    //      load batches -> ~NPT loads in flight, not a serial chain) ----
    int   oi[NPT];
    float val[NPT];
#pragma unroll
    for (int u = 0; u < NPT; ++u) {
        int j = tid + u * TPB;
        oi[u] = (j < n_obs) ? obs_idx[j] : 0;
    }
#pragma unroll
    for (int u = 0; u < NPT; ++u) {
        val[u] = X[oi[u]];
    }
#pragma unroll
    for (int u = 0; u < NPT; ++u) {
        int j = tid + u * TPB;
        if (j < n_obs) obs_s[j] = val[u];
    }
    // safety tail (empty for this problem's sizes)
    for (int j = NPT * TPB + tid; j < n_obs && j < NOBS_MAX; j += TPB)
        obs_s[j] = X[obs_idx[j]];

    // ---- Phase 2: 3 fixed-point iterations ----
    float v = 0.0f;  // reference inits missing entries to 0
    for (int it = 0; it < 3; ++it) {
        // register-resident scan: per-thread top-5
        ull k0 = ~0ull, k1 = ~0ull, k2 = ~0ull, k3 = ~0ull, k4 = ~0ull;
#pragma unroll
        for (int u = 0; u < NPT; ++u) {
            int j = tid + u * TPB;
            float diff = v - val[u];
            float d = diff * diff;
            ull key = ((ull)__float_as_uint(d) << 32) | (unsigned int)j;
            if (j >= n_obs) key = ~0ull;
            insert5(key, k0, k1, k2, k3, k4);
        }
        for (int j = NPT * TPB + tid; j < n_obs && j < NOBS_MAX; j += TPB) {
            float diff = v - obs_s[j];
            float d = diff * diff;
            insert5(((ull)__float_as_uint(d) << 32) | (unsigned int)j, k0, k1, k2, k3, k4);
        }

        // wave-level reduce: 6 rounds of 64-bit shfl_xor butterfly merge
        for (int mask = 1; mask < 64; mask <<= 1) {
            ull b0 = __shfl_xor(k0, mask, 64);
            ull b1 = __shfl_xor(k1, mask, 64);
            ull b2 = __shfl_xor(k2, mask, 64);
            ull b3 = __shfl_xor(k3, mask, 64);
            ull b4 = __shfl_xor(k4, mask, 64);
            merge5(k0, k1, k2, k3, k4, b0, b1, b2, b3, b4);
        }
        if (lane == 0) {
            sk[wid * 5 + 0] = k0; sk[wid * 5 + 1] = k1; sk[wid * 5 + 2] = k2;
            sk[wid * 5 + 3] = k3; sk[wid * 5 + 4] = k4;
        }
        __syncthreads();

        // cross-wave reduce inside wave 0 (16 lists -> 4 shfl-merge rounds)
        if (wid == 0) {
            ull g0 = ~0ull, g1 = ~0ull, g2 = ~0ull, g3 = ~0ull, g4 = ~0ull;
            if (lane < NWAVE) {
                g0 = sk[lane * 5 + 0]; g1 = sk[lane * 5 + 1]; g2 = sk[lane * 5 + 2];
                g3 = sk[lane * 5 + 3]; g4 = sk[lane * 5 + 4];
            }
            for (int mask = 1; mask < NWAVE; mask <<= 1) {
                ull b0 = __shfl_xor(g0, mask, 64);
                ull b1 = __shfl_xor(g1, mask, 64);
                ull b2 = __shfl_xor(g2, mask, 64);
                ull b3 = __shfl_xor(g3, mask, 64);
                ull b4 = __shfl_xor(g4, mask, 64);
                merge5(g0, g1, g2, g3, g4, b0, b1, b2, b3, b4);
            }
            if (lane == 0) {
                // sum in ascending-distance order (matches reference gather order)
                float s = obs_s[(unsigned int)(g0 & 0xFFFFFFFFull)];
                s += obs_s[(unsigned int)(g1 & 0xFFFFFFFFull)];
                s += obs_s[(unsigned int)(g2 & 0xFFFFFFFFull)];
                s += obs_s[(unsigned int)(g3 & 0xFFFFFFFFull)];
                s += obs_s[(unsigned int)(g4 & 0xFFFFFFFFull)];
                v_sh = s * 0.2f;
            }
        }
        __syncthreads();
        v = v_sh;
        __syncthreads();  // protect sk reuse + v_sh before next iteration's writes
    }

    // ---- Phase 3: scatter the (single) imputed value ----
    for (int j = tid; j < n_miss; j += TPB) out[miss_idx[j]] = v;
}

extern "C" void kernel_launch(void* const* d_in, const int* in_sizes, int n_in,
                              void* d_out, int out_size, void* d_ws, size_t ws_size,
                              hipStream_t stream) {
    const float* X        = (const float*)d_in[0];
    const int*   miss_idx = (const int*)d_in[1];
    const int*   obs_idx  = (const int*)d_in[2];
    float*       out      = (float*)d_out;

    const int n_miss = in_sizes[1];
    const int n_obs  = in_sizes[2];
    const int n      = out_size;

    knn_fused_kernel<<<1, TPB, 0, stream>>>(X, miss_idx, obs_idx, out, n, n_obs, n_miss);
}

// Round 3
// 34.454 us; speedup vs baseline: 2.8801x; 1.3553x over previous
//
#include <hip/hip_runtime.h>
#include <math.h>

#define ATPB 256          // kernel A threads/block
#define ABLK 32           // kernel A blocks
#define BTPB 256          // kernel B threads (1 block)
#define CAP_LDS 8192      // max candidates stageable in LDS

typedef unsigned long long ull;

__device__ __forceinline__ ull umin64(ull a, ull b) { return a < b ? a : b; }
__device__ __forceinline__ ull umax64(ull a, ull b) { return a > b ? a : b; }

// Branchless order-statistic merge of two sorted 5-lists (ascending).
// Keys are unique ((dist_bits<<32)|orig_index) -> total order, exact
// jax.lax.top_k tie-break (lower index wins).
__device__ __forceinline__ void merge5(ull& a0, ull& a1, ull& a2, ull& a3, ull& a4,
                                       ull b0, ull b1, ull b2, ull b3, ull b4) {
    ull m0 = umin64(a0, b0);
    ull m1 = umin64(umin64(a1, b1), umax64(a0, b0));
    ull m2 = umin64(umin64(a2, b2), umin64(umax64(a0, b1), umax64(a1, b0)));
    ull m3 = umin64(umin64(a3, b3),
                    umin64(umin64(umax64(a0, b2), umax64(a1, b1)), umax64(a2, b0)));
    ull m4 = umin64(umin64(a4, b4),
                    umin64(umin64(umax64(a0, b3), umax64(a1, b2)),
                           umin64(umax64(a2, b1), umax64(a3, b0))));
    a0 = m0; a1 = m1; a2 = m2; a3 = m3; a4 = m4;
}

__device__ __forceinline__ void insert5(ull key, ull& k0, ull& k1, ull& k2, ull& k3, ull& k4) {
    if (key < k4) {
        k4 = key;
        ull t;
        if (k4 < k3) { t = k3; k3 = k4; k4 = t; }
        if (k3 < k2) { t = k2; k2 = k3; k3 = t; }
        if (k2 < k1) { t = k1; k1 = k2; k2 = t; }
        if (k1 < k0) { t = k0; k0 = k1; k1 = t; }
    }
}

#define BUTTERFLY64(k0,k1,k2,k3,k4)                                 \
    for (int mask_ = 1; mask_ < 64; mask_ <<= 1) {                  \
        ull b0_ = __shfl_xor(k0, mask_, 64);                        \
        ull b1_ = __shfl_xor(k1, mask_, 64);                        \
        ull b2_ = __shfl_xor(k2, mask_, 64);                        \
        ull b3_ = __shfl_xor(k3, mask_, 64);                        \
        ull b4_ = __shfl_xor(k4, mask_, 64);                        \
        merge5(k0, k1, k2, k3, k4, b0_, b1_, b2_, b3_, b4_);        \
    }

// Kernel A (parallel): copy X->out, and build the candidate set.
// Bound proof (v0=0): r0 = global 5th-smallest |x|. |v1|<=r0, d5(v1)<=2r0,
// so 5NN(v1) has |x|<=3r0; |v2|<=3r0, d5(v2)<=4r0, so 5NN(v2) has |x|<=7r0.
// Each block filters with 8*r_loc where r_loc (its local 5th-smallest |x|)
// >= r0, hence keeps a superset of everything any iteration can select.
__global__ void __launch_bounds__(ATPB) knn_prep_kernel(
    const float* __restrict__ X, const int* __restrict__ obs_idx,
    float* __restrict__ out, float* __restrict__ candx, int* __restrict__ candj,
    int* __restrict__ cnt, int n, int n_obs, int cap)
{
    const int tid  = threadIdx.x;
    const int b    = blockIdx.x;
    const int gtid = b * ATPB + tid;
    const int gsz  = gridDim.x * ATPB;

    // ---- copy X -> out (float4 + tail) ----
    const int n4 = n >> 2;
    for (int i = gtid; i < n4; i += gsz)
        reinterpret_cast<float4*>(out)[i] = reinterpret_cast<const float4*>(X)[i];
    for (int t = (n4 << 2) + gtid; t < n; t += gsz) out[t] = X[t];

    // ---- this block's contiguous slice of observed values ----
    const int per = (n_obs + ABLK - 1) / ABLK;      // 922 for this problem
    const int j0  = b * per;
    const int j1  = min(j0 + per, n_obs);

    int   oj[4];
    float xv[4];
#pragma unroll
    for (int u = 0; u < 4; ++u) {
        int j = j0 + tid + u * ATPB;
        oj[u] = (j < j1) ? obs_idx[j] : 0;
    }
#pragma unroll
    for (int u = 0; u < 4; ++u) xv[u] = X[oj[u]];

    // ---- local top-5 by x^2 (distance to 0) ----
    ull k0 = ~0ull, k1 = ~0ull, k2 = ~0ull, k3 = ~0ull, k4 = ~0ull;
#pragma unroll
    for (int u = 0; u < 4; ++u) {
        int j = j0 + tid + u * ATPB;
        if (j < j1) {
            float d = xv[u] * xv[u];
            insert5(((ull)__float_as_uint(d) << 32) | (unsigned)j, k0, k1, k2, k3, k4);
        }
    }
    BUTTERFLY64(k0, k1, k2, k3, k4)

    __shared__ ull   sk[(ATPB / 64) * 5];
    __shared__ float thr_sh;
    const int wid = tid >> 6, lane = tid & 63;
    if (lane == 0) {
        sk[wid * 5 + 0] = k0; sk[wid * 5 + 1] = k1; sk[wid * 5 + 2] = k2;
        sk[wid * 5 + 3] = k3; sk[wid * 5 + 4] = k4;
    }
    __syncthreads();
    if (wid == 0) {
        ull g0 = ~0ull, g1 = ~0ull, g2 = ~0ull, g3 = ~0ull, g4 = ~0ull;
        if (lane < ATPB / 64) {
            g0 = sk[lane * 5 + 0]; g1 = sk[lane * 5 + 1]; g2 = sk[lane * 5 + 2];
            g3 = sk[lane * 5 + 3]; g4 = sk[lane * 5 + 4];
        }
        for (int mask = 1; mask < ATPB / 64; mask <<= 1) {
            ull b0 = __shfl_xor(g0, mask, 64);
            ull b1 = __shfl_xor(g1, mask, 64);
            ull b2 = __shfl_xor(g2, mask, 64);
            ull b3 = __shfl_xor(g3, mask, 64);
            ull b4 = __shfl_xor(g4, mask, 64);
            merge5(g0, g1, g2, g3, g4, b0, b1, b2, b3, b4);
        }
        if (lane == 0) {
            float d5 = __uint_as_float((unsigned)(g4 >> 32));   // local r_loc^2
            thr_sh = (d5 < INFINITY) ? 64.0f * d5 : INFINITY;   // (8*r_loc)^2; NaN/inf -> keep all (conservative)
        }
    }
    __syncthreads();
    const float thr = thr_sh;

    // ---- append candidates (x^2 <= 64*r_loc^2) ----
#pragma unroll
    for (int u = 0; u < 4; ++u) {
        int j = j0 + tid + u * ATPB;
        if (j < j1 && xv[u] * xv[u] <= thr) {
            int pos = atomicAdd(cnt, 1);
            if (pos < cap) { candx[pos] = xv[u]; candj[pos] = j; }
        }
    }
}

// Kernel B (1 block): 3 exact fixed-point iterations over the candidate set
// (fallback: full gather scan if the candidate set overflowed), then scatter.
__global__ void __launch_bounds__(BTPB) knn_solve_kernel(
    const float* __restrict__ X, const int* __restrict__ miss_idx,
    const int* __restrict__ obs_idx,
    const float* __restrict__ candx, const int* __restrict__ candj,
    const int* __restrict__ cnt, float* __restrict__ out,
    int n_obs, int n_miss, int cap)
{
    __shared__ float cxs[CAP_LDS];
    __shared__ int   cjs[CAP_LDS];
    __shared__ ull   sk[(BTPB / 64) * 5];
    __shared__ float v_sh;

    const int tid = threadIdx.x, wid = tid >> 6, lane = tid & 63;

    const int  c    = *cnt;
    const bool usec = (c >= 5) && (c <= cap) && (c <= CAP_LDS);
    const int  M    = usec ? c : n_obs;

    if (usec)
        for (int e = tid; e < c; e += BTPB) { cxs[e] = candx[e]; cjs[e] = candj[e]; }
    __syncthreads();

    float v = 0.0f;  // reference inits missing entries to 0
    for (int it = 0; it < 3; ++it) {
        ull k0 = ~0ull, k1 = ~0ull, k2 = ~0ull, k3 = ~0ull, k4 = ~0ull;
        for (int e = tid; e < M; e += BTPB) {
            float x; unsigned j;
            if (usec) { x = cxs[e]; j = (unsigned)cjs[e]; }
            else      { j = (unsigned)e; x = X[obs_idx[e]]; }   // slow exact fallback
            float diff = v - x;
            float d = diff * diff;
            insert5(((ull)__float_as_uint(d) << 32) | j, k0, k1, k2, k3, k4);
        }
        BUTTERFLY64(k0, k1, k2, k3, k4)

        if (lane == 0) {
            sk[wid * 5 + 0] = k0; sk[wid * 5 + 1] = k1; sk[wid * 5 + 2] = k2;
            sk[wid * 5 + 3] = k3; sk[wid * 5 + 4] = k4;
        }
        __syncthreads();

        if (wid == 0) {
            ull g0 = ~0ull, g1 = ~0ull, g2 = ~0ull, g3 = ~0ull, g4 = ~0ull;
            if (lane < BTPB / 64) {
                g0 = sk[lane * 5 + 0]; g1 = sk[lane * 5 + 1]; g2 = sk[lane * 5 + 2];
                g3 = sk[lane * 5 + 3]; g4 = sk[lane * 5 + 4];
            }
            for (int mask = 1; mask < BTPB / 64; mask <<= 1) {
                ull b0 = __shfl_xor(g0, mask, 64);
                ull b1 = __shfl_xor(g1, mask, 64);
                ull b2 = __shfl_xor(g2, mask, 64);
                ull b3 = __shfl_xor(g3, mask, 64);
                ull b4 = __shfl_xor(g4, mask, 64);
                merge5(g0, g1, g2, g3, g4, b0, b1, b2, b3, b4);
            }
            // broadcast the 5 winner keys, gather their values in parallel lanes
            ull h0 = __shfl(g0, 0, 64), h1 = __shfl(g1, 0, 64), h2 = __shfl(g2, 0, 64),
                h3 = __shfl(g3, 0, 64), h4 = __shfl(g4, 0, 64);
            float xx = 0.0f;
            if (lane < 5) {
                ull key = (lane == 0) ? h0 : (lane == 1) ? h1 : (lane == 2) ? h2
                         : (lane == 3) ? h3 : h4;
                int jj = (int)(unsigned)(key & 0xFFFFFFFFull);
                xx = X[obs_idx[jj]];
            }
            float x0 = __shfl(xx, 0, 64), x1 = __shfl(xx, 1, 64), x2 = __shfl(xx, 2, 64),
                  x3 = __shfl(xx, 3, 64), x4 = __shfl(xx, 4, 64);
            if (lane == 0) {
                // sum in ascending (dist,idx) order — matches reference exactly (R2: absmax 0.0)
                float s = x0; s += x1; s += x2; s += x3; s += x4;
                v_sh = s * 0.2f;
            }
        }
        __syncthreads();
        v = v_sh;
        // next iteration's sk writes happen after this barrier in program order;
        // wid0's sk reads completed before it -> 2 barriers/iter suffice
    }

    for (int m = tid; m < n_miss; m += BTPB) out[miss_idx[m]] = v;
}

extern "C" void kernel_launch(void* const* d_in, const int* in_sizes, int n_in,
                              void* d_out, int out_size, void* d_ws, size_t ws_size,
                              hipStream_t stream) {
    const float* X        = (const float*)d_in[0];
    const int*   miss_idx = (const int*)d_in[1];
    const int*   obs_idx  = (const int*)d_in[2];
    float*       out      = (float*)d_out;

    const int n_miss = in_sizes[1];
    const int n_obs  = in_sizes[2];
    const int n      = out_size;

    // workspace layout: [0..4) counter | [64 ..) candx[cap] | then candj[cap]
    char* ws  = (char*)d_ws;
    long  avail = (ws_size > 64) ? (long)((ws_size - 64) / 8) : 0;
    int   cap  = (int)((avail < (long)CAP_LDS) ? avail : (long)CAP_LDS);
    if (cap < 0) cap = 0;
    int*   cnt   = (int*)ws;
    float* candx = (float*)(ws + 64);
    int*   candj = (int*)(ws + 64 + (size_t)cap * sizeof(float));

    hipMemsetAsync(cnt, 0, sizeof(int), stream);
    knn_prep_kernel<<<ABLK, ATPB, 0, stream>>>(X, obs_idx, out, candx, candj, cnt,
                                               n, n_obs, cap);
    knn_solve_kernel<<<1, BTPB, 0, stream>>>(X, miss_idx, obs_idx, candx, candj, cnt,
                                             out, n_obs, n_miss, cap);
}

// Round 4
// 26.875 us; speedup vs baseline: 3.6922x; 1.2820x over previous
//
#include <hip/hip_runtime.h>
#include <math.h>

#define ATPB 256          // prep threads/block
#define ABLK 32           // prep blocks
#define BTPB 512          // solve threads (1 block)
#define CAP_LDS 2048      // max total candidates staged in solve LDS
#define PERCAP 256        // candidate slots per prep block (expected ~40 used)

typedef unsigned long long ull;

__device__ __forceinline__ ull umin64(ull a, ull b) { return a < b ? a : b; }
__device__ __forceinline__ ull umax64(ull a, ull b) { return a > b ? a : b; }

// Branchless order-statistic merge of two sorted 5-lists (ascending).
// Keys are unique -> total order; low tie-break bits = candidate order =
// original-index order, exactly matching jax.lax.top_k semantics.
__device__ __forceinline__ void merge5(ull& a0, ull& a1, ull& a2, ull& a3, ull& a4,
                                       ull b0, ull b1, ull b2, ull b3, ull b4) {
    ull m0 = umin64(a0, b0);
    ull m1 = umin64(umin64(a1, b1), umax64(a0, b0));
    ull m2 = umin64(umin64(a2, b2), umin64(umax64(a0, b1), umax64(a1, b0)));
    ull m3 = umin64(umin64(a3, b3),
                    umin64(umin64(umax64(a0, b2), umax64(a1, b1)), umax64(a2, b0)));
    ull m4 = umin64(umin64(a4, b4),
                    umin64(umin64(umax64(a0, b3), umax64(a1, b2)),
                           umin64(umax64(a2, b1), umax64(a3, b0))));
    a0 = m0; a1 = m1; a2 = m2; a3 = m3; a4 = m4;
}

__device__ __forceinline__ void insert5(ull key, ull& k0, ull& k1, ull& k2, ull& k3, ull& k4) {
    if (key < k4) {
        k4 = key;
        ull t;
        if (k4 < k3) { t = k3; k3 = k4; k4 = t; }
        if (k3 < k2) { t = k2; k2 = k3; k3 = t; }
        if (k2 < k1) { t = k1; k1 = k2; k2 = t; }
        if (k1 < k0) { t = k0; k0 = k1; k1 = t; }
    }
}

#define BUTTERFLY(kk0,kk1,kk2,kk3,kk4,WIDTH)                        \
    for (int mask_ = 1; mask_ < (WIDTH); mask_ <<= 1) {             \
        ull b0_ = __shfl_xor(kk0, mask_, 64);                       \
        ull b1_ = __shfl_xor(kk1, mask_, 64);                       \
        ull b2_ = __shfl_xor(kk2, mask_, 64);                       \
        ull b3_ = __shfl_xor(kk3, mask_, 64);                       \
        ull b4_ = __shfl_xor(kk4, mask_, 64);                       \
        merge5(kk0, kk1, kk2, kk3, kk4, b0_, b1_, b2_, b3_, b4_);   \
    }

// ---------------------------------------------------------------------------
// Kernel A: copy X->out + build candidate set (per-block regions, no atomics,
// no initialization required: counts[b] is overwritten unconditionally).
// Bound proof (v0=0): r0 = global 5th-smallest |x|. |v1|<=r0, d5(v1)<=2r0 ->
// 5NN(v1) within |x|<=3r0; |v2|<=3r0, d5(v2)<=4r0 -> 5NN(v2) within |x|<=7r0.
// Block filter keeps |x| <= 8*r_loc, r_loc >= r0 -> guaranteed superset.
// ---------------------------------------------------------------------------
__global__ void __launch_bounds__(ATPB) knn_prep_kernel(
    const float* __restrict__ X, const int* __restrict__ obs_idx,
    float* __restrict__ out, uint2* __restrict__ cand, int* __restrict__ counts,
    int n, int n_obs, int per, int percap)
{
    const int tid  = threadIdx.x;
    const int b    = blockIdx.x;
    const int gtid = b * ATPB + tid;
    const int gsz  = ABLK * ATPB;

    // ---- copy X -> out (float4 + tail) ----
    const int n4 = n >> 2;
    for (int i = gtid; i < n4; i += gsz)
        reinterpret_cast<float4*>(out)[i] = reinterpret_cast<const float4*>(X)[i];
    for (int t = (n4 << 2) + gtid; t < n; t += gsz) out[t] = X[t];

    // ---- gather this block's slice of observed values ----
    const int j0 = b * per;
    const int j1 = min(j0 + per, n_obs);

    int   oj[4];
    float xv[4];
#pragma unroll
    for (int u = 0; u < 4; ++u) {
        int j = j0 + tid + u * ATPB;
        oj[u] = (j < j1) ? obs_idx[j] : 0;
    }
#pragma unroll
    for (int u = 0; u < 4; ++u) xv[u] = X[oj[u]];

    // ---- block-local top-5 by x^2 ----
    ull k0 = ~0ull, k1 = ~0ull, k2 = ~0ull, k3 = ~0ull, k4 = ~0ull;
#pragma unroll
    for (int u = 0; u < 4; ++u) {
        int j = j0 + tid + u * ATPB;
        if (j < j1) {
            float d = xv[u] * xv[u];
            insert5(((ull)__float_as_uint(d) << 32) | (unsigned)j, k0, k1, k2, k3, k4);
        }
    }
    BUTTERFLY(k0, k1, k2, k3, k4, 64)

    __shared__ ull   sk[(ATPB / 64) * 5];
    __shared__ float thr_sh;
    __shared__ int   wcnt[ATPB / 64];
    const int wid = tid >> 6, lane = tid & 63;
    if (lane == 0) {
        sk[wid * 5 + 0] = k0; sk[wid * 5 + 1] = k1; sk[wid * 5 + 2] = k2;
        sk[wid * 5 + 3] = k3; sk[wid * 5 + 4] = k4;
    }
    __syncthreads();
    if (wid == 0) {
        ull g0 = ~0ull, g1 = ~0ull, g2 = ~0ull, g3 = ~0ull, g4 = ~0ull;
        if (lane < ATPB / 64) {
            g0 = sk[lane * 5 + 0]; g1 = sk[lane * 5 + 1]; g2 = sk[lane * 5 + 2];
            g3 = sk[lane * 5 + 3]; g4 = sk[lane * 5 + 4];
        }
        BUTTERFLY(g0, g1, g2, g3, g4, ATPB / 64)
        if (lane == 0) {
            float d5 = __uint_as_float((unsigned)(g4 >> 32));   // r_loc^2
            thr_sh = (d5 < INFINITY) ? 64.0f * d5 : INFINITY;   // (8*r_loc)^2
        }
    }
    __syncthreads();
    const float thr = thr_sh;
    const ull lanemask_lt = (1ull << lane) - 1ull;

    // ---- order-preserving compaction into this block's region ----
    int base = 0;
#pragma unroll
    for (int u = 0; u < 4; ++u) {
        int  j    = j0 + tid + u * ATPB;
        bool keep = (j < j1) && (xv[u] * xv[u] <= thr);
        ull  mask = __ballot(keep);
        if (lane == 0) wcnt[wid] = (int)__popcll(mask);
        __syncthreads();
        int wbase = 0, utotal = 0;
#pragma unroll
        for (int w = 0; w < ATPB / 64; ++w) {
            if (w == wid) wbase = utotal;
            utotal += wcnt[w];
        }
        int pos = base + wbase + (int)__popcll(mask & lanemask_lt);
        if (keep && pos < percap)
            cand[b * percap + pos] = make_uint2(__float_as_uint(xv[u]), (unsigned)j);
        base += utotal;
        __syncthreads();
    }
    if (tid == 0 && percap >= 0) counts[b] = base;   // may exceed percap -> fallback
}

// ---------------------------------------------------------------------------
// Kernel B (1 block): 3 exact fixed-point iterations over the candidates,
// then scatter. Winner values resolved by LDS match (no global loads).
// ---------------------------------------------------------------------------
__global__ void __launch_bounds__(BTPB) knn_solve_kernel(
    const float* __restrict__ X, const int* __restrict__ miss_idx,
    const int* __restrict__ obs_idx, const uint2* __restrict__ cand,
    const int* __restrict__ counts, float* __restrict__ out,
    int n_obs, int n_miss, int percap)
{
    __shared__ uint2 cs[CAP_LDS];
    __shared__ int   carr[ABLK];
    __shared__ ull   sk[(BTPB / 64) * 5];
    __shared__ ull   wk[5];
    __shared__ float vals[5];
    __shared__ float v_sh;

    const int tid = threadIdx.x, wid = tid >> 6, lane = tid & 63;

    if (tid < ABLK) carr[tid] = (percap > 0) ? counts[tid] : (percap <= 0 ? 0x7FFFFFFF : 0);
    __syncthreads();

    // every thread derives: total C, its staging base, overflow flag
    int C = 0, bad = (percap <= 0);
    const int myb = tid >> 4;                 // 16 staging threads per region
    int mybase = 0;
#pragma unroll
    for (int b2 = 0; b2 < ABLK; ++b2) {
        int c2 = carr[b2];
        if (b2 == myb) mybase = C;
        C += c2;
        if (c2 > percap) bad = 1;
    }
    const bool usec = !bad && (C >= 5) && (C <= CAP_LDS);

    if (usec) {
        const int cb = carr[myb];
        for (int e = (tid & 15); e < cb; e += 16)
            cs[mybase + e] = cand[myb * percap + e];
    }
    __syncthreads();

    float v = 0.0f;  // reference inits missing entries to 0

    if (usec) {
        // cache candidate values in registers (slot order == original-j order)
        float cx[4];
#pragma unroll
        for (int k = 0; k < 4; ++k) {
            int e = tid + k * BTPB;
            cx[k] = (e < C) ? __uint_as_float(cs[e].x) : 0.0f;
        }

        for (int it = 0; it < 3; ++it) {
            ull k0 = ~0ull, k1 = ~0ull, k2 = ~0ull, k3 = ~0ull, k4 = ~0ull;
#pragma unroll
            for (int k = 0; k < 4; ++k) {
                int e = tid + k * BTPB;
                if (e < C) {
                    float diff = v - cx[k];
                    float d = diff * diff;
                    // slot index e: same total order & tie-break as original j
                    insert5(((ull)__float_as_uint(d) << 32) | (unsigned)e,
                            k0, k1, k2, k3, k4);
                }
            }
            BUTTERFLY(k0, k1, k2, k3, k4, 64)
            if (lane == 0) {
                sk[wid * 5 + 0] = k0; sk[wid * 5 + 1] = k1; sk[wid * 5 + 2] = k2;
                sk[wid * 5 + 3] = k3; sk[wid * 5 + 4] = k4;
            }
            __syncthreads();
            if (wid == 0) {
                ull g0 = ~0ull, g1 = ~0ull, g2 = ~0ull, g3 = ~0ull, g4 = ~0ull;
                if (lane < BTPB / 64) {
                    g0 = sk[lane * 5 + 0]; g1 = sk[lane * 5 + 1]; g2 = sk[lane * 5 + 2];
                    g3 = sk[lane * 5 + 3]; g4 = sk[lane * 5 + 4];
                }
                BUTTERFLY(g0, g1, g2, g3, g4, BTPB / 64)
                if (lane == 0) {
                    wk[0] = g0; wk[1] = g1; wk[2] = g2; wk[3] = g3; wk[4] = g4;
                }
            }
            __syncthreads();
            // winner-value match from register cache (unique slots -> no race)
            int wj0 = (int)(unsigned)(wk[0] & 0xFFFFFFFFull);
            int wj1 = (int)(unsigned)(wk[1] & 0xFFFFFFFFull);
            int wj2 = (int)(unsigned)(wk[2] & 0xFFFFFFFFull);
            int wj3 = (int)(unsigned)(wk[3] & 0xFFFFFFFFull);
            int wj4 = (int)(unsigned)(wk[4] & 0xFFFFFFFFull);
#pragma unroll
            for (int k = 0; k < 4; ++k) {
                int e = tid + k * BTPB;
                if (e < C) {
                    if (e == wj0) vals[0] = cx[k];
                    if (e == wj1) vals[1] = cx[k];
                    if (e == wj2) vals[2] = cx[k];
                    if (e == wj3) vals[3] = cx[k];
                    if (e == wj4) vals[4] = cx[k];
                }
            }
            __syncthreads();
            if (tid == 0) {
                // ascending (dist, idx) order — matches reference sum order
                float s = vals[0]; s += vals[1]; s += vals[2]; s += vals[3]; s += vals[4];
                v_sh = s * 0.2f;
            }
            __syncthreads();
            v = v_sh;
            __syncthreads();
        }
    } else {
        // exact full-scan fallback (never expected to trigger)
        for (int it = 0; it < 3; ++it) {
            ull k0 = ~0ull, k1 = ~0ull, k2 = ~0ull, k3 = ~0ull, k4 = ~0ull;
            for (int e = tid; e < n_obs; e += BTPB) {
                float x = X[obs_idx[e]];
                float diff = v - x;
                float d = diff * diff;
                insert5(((ull)__float_as_uint(d) << 32) | (unsigned)e, k0, k1, k2, k3, k4);
            }
            BUTTERFLY(k0, k1, k2, k3, k4, 64)
            if (lane == 0) {
                sk[wid * 5 + 0] = k0; sk[wid * 5 + 1] = k1; sk[wid * 5 + 2] = k2;
                sk[wid * 5 + 3] = k3; sk[wid * 5 + 4] = k4;
            }
            __syncthreads();
            if (wid == 0) {
                ull g0 = ~0ull, g1 = ~0ull, g2 = ~0ull, g3 = ~0ull, g4 = ~0ull;
                if (lane < BTPB / 64) {
                    g0 = sk[lane * 5 + 0]; g1 = sk[lane * 5 + 1]; g2 = sk[lane * 5 + 2];
                    g3 = sk[lane * 5 + 3]; g4 = sk[lane * 5 + 4];
                }
                BUTTERFLY(g0, g1, g2, g3, g4, BTPB / 64)
                ull h0 = __shfl(g0, 0, 64), h1 = __shfl(g1, 0, 64), h2 = __shfl(g2, 0, 64),
                    h3 = __shfl(g3, 0, 64), h4 = __shfl(g4, 0, 64);
                float xx = 0.0f;
                if (lane < 5) {
                    ull key = (lane == 0) ? h0 : (lane == 1) ? h1 : (lane == 2) ? h2
                             : (lane == 3) ? h3 : h4;
                    int jj = (int)(unsigned)(key & 0xFFFFFFFFull);
                    xx = X[obs_idx[jj]];
                }
                float x0 = __shfl(xx, 0, 64), x1 = __shfl(xx, 1, 64), x2 = __shfl(xx, 2, 64),
                      x3 = __shfl(xx, 3, 64), x4 = __shfl(xx, 4, 64);
                if (lane == 0) {
                    float s = x0; s += x1; s += x2; s += x3; s += x4;
                    v_sh = s * 0.2f;
                }
            }
            __syncthreads();
            v = v_sh;
            __syncthreads();
        }
    }

    // scatter the single imputed value
    for (int m = tid; m < n_miss; m += BTPB) out[miss_idx[m]] = v;
}

extern "C" void kernel_launch(void* const* d_in, const int* in_sizes, int n_in,
                              void* d_out, int out_size, void* d_ws, size_t ws_size,
                              hipStream_t stream) {
    const float* X        = (const float*)d_in[0];
    const int*   miss_idx = (const int*)d_in[1];
    const int*   obs_idx  = (const int*)d_in[2];
    float*       out      = (float*)d_out;

    const int n_miss = in_sizes[1];
    const int n_obs  = in_sizes[2];
    const int n      = out_size;
    const int per    = (n_obs + ABLK - 1) / ABLK;

    // ws layout: counts[32] at 0 (256B-aligned region), cand[] at 256.
    int percap = PERCAP;
    size_t need = 256 + (size_t)ABLK * PERCAP * sizeof(uint2);
    if (ws_size < need) {
        if (ws_size >= 512)
            percap = (int)((ws_size - 256) / (ABLK * sizeof(uint2)));
        else
            percap = -1;   // no usable ws: force exact fallback
    }
    int*   counts = (int*)d_ws;
    uint2* cand   = (uint2*)((char*)d_ws + 256);

    knn_prep_kernel<<<ABLK, ATPB, 0, stream>>>(X, obs_idx, out, cand, counts,
                                               n, n_obs, per, percap);
    knn_solve_kernel<<<1, BTPB, 0, stream>>>(X, miss_idx, obs_idx, cand, counts,
                                             out, n_obs, n_miss, percap);
}